// Round 3
// baseline (364.678 us; speedup 1.0000x reference)
//
#include <hip/hip_runtime.h>

// LiquidNet (LTC) on MI355X.
// Structure: sensory partial-sums -> 6x (step partial-sums -> finalize).
// All reductions are sigmoid-inside-sum -> VALU/transcendental bound, no MFMA.

constexpr int B_ = 64;
constexpr int F_ = 256;
constexpr int H_ = 768;
constexpr int UNFOLDS_ = 6;

constexpr int BB = 16;                  // batches per thread (weight reuse x16)
constexpr int JT = 256;                 // threads per block == j columns per block
constexpr int IC_STEP = 32;             // i's per chunk in step kernel
constexpr int SCH_STEP = H_ / IC_STEP;  // 24 chunks -> grid 3*4*24 = 288 blocks
constexpr int IC_SENS = 16;             // f's per chunk in sensory kernel
constexpr int SCH_SENS = F_ / IC_SENS;  // 16 chunks -> grid 3*4*16 = 192 blocks

// ---------------------------------------------------------------- sensory ---
__global__ __launch_bounds__(JT) void sensory_partial_k(
    const float* __restrict__ inputs, const float* __restrict__ iw,
    const float* __restrict__ ib,
    const float* __restrict__ smu, const float* __restrict__ ssig,
    const float* __restrict__ sW, const float* __restrict__ serev,
    float* __restrict__ part)  // [num|den][SCH_SENS][B][H]
{
    const int j  = blockIdx.x * JT + threadIdx.x;
    const int b0 = blockIdx.y * BB;
    const int f0 = blockIdx.z * IC_SENS;

    __shared__ float xs[BB][IC_SENS];
    {
        // BB*IC_SENS == 256 == JT: one element per thread
        int t  = threadIdx.x;
        int bb = t / IC_SENS, ii = t % IC_SENS;
        int f  = f0 + ii;
        xs[bb][ii] = fmaf(inputs[(b0 + bb) * F_ + f], iw[f], ib[f]);
    }
    __syncthreads();

    float num[BB], den[BB];
#pragma unroll
    for (int k = 0; k < BB; ++k) { num[k] = 0.f; den[k] = 0.f; }

    const float L2E = 1.44269504088896f;
#pragma unroll 2
    for (int ii = 0; ii < IC_SENS; ++ii) {
        const int idx = (f0 + ii) * H_ + j;
        float sg = ssig[idx], m = smu[idx], w = sW[idx], e = serev[idx];
        float sg2 = sg * L2E;       // fold log2(e) into sigma -> native v_exp_f32
        float c   = sg2 * m;
        float we  = w * e;
#pragma unroll
        for (int k = 0; k < BB; ++k) {
            float t  = fmaf(-sg2, xs[k][ii], c);          // = -log2e*sigma*(x - mu)
            float ex = __builtin_amdgcn_exp2f(t);         // exp(-z), native v_exp_f32
            float s  = __builtin_amdgcn_rcpf(1.0f + ex);  // sigmoid(z)
            den[k] = fmaf(w,  s, den[k]);
            num[k] = fmaf(we, s, num[k]);
        }
    }

    float* pnum = part;
    float* pden = part + SCH_SENS * B_ * H_;
    const int base = (blockIdx.z * B_ + b0) * H_ + j;
#pragma unroll
    for (int k = 0; k < BB; ++k) {
        pnum[base + k * H_] = num[k];
        pden[base + k * H_] = den[k];
    }
}

// ------------------------------------------------------------------- step ---
__global__ __launch_bounds__(JT) void step_partial_k(
    const float* __restrict__ v_in,
    const float* __restrict__ mu, const float* __restrict__ sigma,
    const float* __restrict__ W, const float* __restrict__ erev,
    float* __restrict__ part)  // [num|den][SCH_STEP][B][H]
{
    const int j  = blockIdx.x * JT + threadIdx.x;
    const int b0 = blockIdx.y * BB;
    const int i0 = blockIdx.z * IC_STEP;

    __shared__ float vs[BB][IC_STEP];
    // BB*IC_STEP == 512: two elements per thread
    for (int t = threadIdx.x; t < BB * IC_STEP; t += JT) {
        int bb = t / IC_STEP, ii = t % IC_STEP;
        vs[bb][ii] = v_in[(b0 + bb) * H_ + i0 + ii];
    }
    __syncthreads();

    float num[BB], den[BB];
#pragma unroll
    for (int k = 0; k < BB; ++k) { num[k] = 0.f; den[k] = 0.f; }

    const float L2E = 1.44269504088896f;
#pragma unroll 2
    for (int ii = 0; ii < IC_STEP; ++ii) {
        const int idx = (i0 + ii) * H_ + j;
        float sg = sigma[idx], m = mu[idx], w = W[idx], e = erev[idx];
        float sg2 = sg * L2E;
        float c   = sg2 * m;
        float we  = w * e;
#pragma unroll
        for (int k = 0; k < BB; ++k) {
            float t  = fmaf(-sg2, vs[k][ii], c);
            float ex = __builtin_amdgcn_exp2f(t);
            float s  = __builtin_amdgcn_rcpf(1.0f + ex);
            den[k] = fmaf(w,  s, den[k]);
            num[k] = fmaf(we, s, num[k]);
        }
    }

    float* pnum = part;
    float* pden = part + SCH_STEP * B_ * H_;
    const int base = (blockIdx.z * B_ + b0) * H_ + j;
#pragma unroll
    for (int k = 0; k < BB; ++k) {
        pnum[base + k * H_] = num[k];
        pden[base + k * H_] = den[k];
    }
}

// --------------------------------------------------------------- finalize ---
__global__ __launch_bounds__(JT) void finalize_k(
    const float* __restrict__ v_in,
    const float* __restrict__ step_part,
    const float* __restrict__ sens_part,
    const float* __restrict__ vleak, const float* __restrict__ gleak,
    const float* __restrict__ cm,
    float* __restrict__ v_out,
    float* __restrict__ out0, float* __restrict__ out1, int write_out)
{
    const int t = blockIdx.x * JT + threadIdx.x;  // t over B*H
    const int j = t % H_;

    float num = 0.f, den = 0.f;
    const float* pnum = step_part;
    const float* pden = step_part + SCH_STEP * B_ * H_;
#pragma unroll
    for (int s = 0; s < SCH_STEP; ++s) {
        num += pnum[s * B_ * H_ + t];
        den += pden[s * B_ * H_ + t];
    }
    const float* snum = sens_part;
    const float* sden = sens_part + SCH_SENS * B_ * H_;
#pragma unroll
    for (int s = 0; s < SCH_SENS; ++s) {
        num += snum[s * B_ * H_ + t];
        den += sden[s * B_ * H_ + t];
    }

    float v  = v_in[t];
    float g  = gleak[j];
    float numer = fmaf(cm[j], v, fmaf(g, vleak[j], num));
    float denom = cm[j] + g + den;
    float vn = numer / denom;
    v_out[t] = vn;
    if (write_out) { out0[t] = vn; out1[t] = vn; }
}

// ----------------------------------------------------------------- launch ---
extern "C" void kernel_launch(void* const* d_in, const int* in_sizes, int n_in,
                              void* d_out, int out_size, void* d_ws, size_t ws_size,
                              hipStream_t stream) {
    const float* inputs = (const float*)d_in[0];
    const float* state  = (const float*)d_in[1];
    const float* iw     = (const float*)d_in[2];
    const float* ib     = (const float*)d_in[3];
    const float* smu    = (const float*)d_in[4];
    const float* ssig   = (const float*)d_in[5];
    const float* sW     = (const float*)d_in[6];
    const float* serev  = (const float*)d_in[7];
    const float* mu     = (const float*)d_in[8];
    const float* sigma  = (const float*)d_in[9];
    const float* W      = (const float*)d_in[10];
    const float* erev   = (const float*)d_in[11];
    const float* vleak  = (const float*)d_in[12];
    const float* gleak  = (const float*)d_in[13];
    const float* cm     = (const float*)d_in[14];
    float* out = (float*)d_out;

    float* ws = (float*)d_ws;
    float* step_part = ws;                                     // 2*SCH_STEP*B*H
    float* sens_part = step_part + 2 * SCH_STEP * B_ * H_;     // 2*SCH_SENS*B*H
    float* v0        = sens_part + 2 * SCH_SENS * B_ * H_;     // B*H
    float* v1        = v0 + B_ * H_;                           // B*H

    dim3 gsens(H_ / JT, B_ / BB, SCH_SENS);
    sensory_partial_k<<<gsens, JT, 0, stream>>>(inputs, iw, ib, smu, ssig, sW,
                                                serev, sens_part);

    const float* vin = state;
    for (int t = 0; t < UNFOLDS_; ++t) {
        dim3 gstep(H_ / JT, B_ / BB, SCH_STEP);
        step_partial_k<<<gstep, JT, 0, stream>>>(vin, mu, sigma, W, erev,
                                                 step_part);
        float* vout = (t & 1) ? v1 : v0;
        int last = (t == UNFOLDS_ - 1);
        finalize_k<<<dim3((B_ * H_) / JT), JT, 0, stream>>>(
            vin, step_part, sens_part, vleak, gleak, cm, vout,
            out, out + B_ * H_, last);
        vin = vout;
    }
}

// Round 4
// 237.344 us; speedup vs baseline: 1.5365x; 1.5365x over previous
//
#include <hip/hip_runtime.h>

// LiquidNet (LTC) on MI355X — fused full-K step kernels.
// sensory_k (1 launch) -> 6x step_k (fused reduction+update, writes v directly).
// 7 launches total, no partial-sum round-trip.
// XCD-aware mapping: xcd = blk & 7 owns j-slice [xcd*96, xcd*96+96) so its
// weight columns stay resident in its private L2 across all 6 unfolds.

constexpr int B_ = 64;
constexpr int F_ = 256;
constexpr int H_ = 768;
constexpr int UNFOLDS_ = 6;

constexpr int BB  = 4;    // batches per block
constexpr int JB  = 32;   // j columns per block
constexpr int NSL = 8;    // reduction slices per block (256 threads / 32 j)
constexpr int NBLK = 384; // 8 xcd * 3 jt * 16 bgroups
constexpr int ISL = H_ / NSL;  // 96 i per slice (step)
constexpr int FSL = F_ / NSL;  // 32 f per slice (sensory)

__device__ __forceinline__ void block_map(int blk, int& j0, int& b0) {
    int xcd = blk & 7;
    int kk  = blk >> 3;          // 0..47
    j0 = xcd * 96 + (kk % 3) * JB;
    b0 = (kk / 3) * BB;
}

// ---------------------------------------------------------------- sensory ---
__global__ __launch_bounds__(256) void sensory_k(
    const float* __restrict__ inputs, const float* __restrict__ iw,
    const float* __restrict__ ib,
    const float* __restrict__ smu, const float* __restrict__ ssig,
    const float* __restrict__ sW, const float* __restrict__ serev,
    float* __restrict__ sens_num, float* __restrict__ sens_den)
{
    int j0, b0;
    block_map(blockIdx.x, j0, b0);
    const int tid = threadIdx.x;
    const int jl = tid & (JB - 1), sl = tid / JB;
    const int j = j0 + jl;

    __shared__ float xs[BB][F_];                 // 4 KB
    __shared__ float red[2][NSL][BB][JB];        // 8 KB

    for (int idx = tid; idx < BB * F_; idx += 256) {
        int b = idx >> 8, f = idx & (F_ - 1);
        xs[b][f] = fmaf(inputs[(b0 + b) * F_ + f], iw[f], ib[f]);
    }
    __syncthreads();

    const float L2E = 1.44269504088896f;
    float num[BB] = {0.f, 0.f, 0.f, 0.f}, den[BB] = {0.f, 0.f, 0.f, 0.f};
    const int fbase = sl * FSL;

    // manual 1-deep prefetch of the 4 weight streams
    int idx0 = fbase * H_ + j;
    float sg = ssig[idx0], m = smu[idx0], w = sW[idx0], e = serev[idx0];
    for (int ff = 0; ff < FSL; ++ff) {
        float sgc = sg, mc = m, wc = w, ec = e;
        if (ff + 1 < FSL) {
            int idx = (fbase + ff + 1) * H_ + j;
            sg = ssig[idx]; m = smu[idx]; w = sW[idx]; e = serev[idx];
        }
        float sg2 = sgc * L2E;
        float c   = sg2 * mc;
        float we  = wc * ec;
#pragma unroll
        for (int k = 0; k < BB; ++k) {
            float t  = fmaf(-sg2, xs[k][fbase + ff], c);
            float ex = __builtin_amdgcn_exp2f(t);         // e^{-z}
            float s  = __builtin_amdgcn_rcpf(1.0f + ex);  // sigmoid(z)
            den[k] = fmaf(wc, s, den[k]);
            num[k] = fmaf(we, s, num[k]);
        }
    }
#pragma unroll
    for (int k = 0; k < BB; ++k) {
        red[0][sl][k][jl] = num[k];
        red[1][sl][k][jl] = den[k];
    }
    __syncthreads();

    if (tid < BB * JB) {   // 128 threads: one output each
        int k = tid / JB, l = tid & (JB - 1);
        float n = 0.f, d = 0.f;
#pragma unroll
        for (int s = 0; s < NSL; ++s) { n += red[0][s][k][l]; d += red[1][s][k][l]; }
        int o = (b0 + k) * H_ + j0 + l;
        sens_num[o] = n;
        sens_den[o] = d;
    }
}

// ------------------------------------------------------------ fused step ---
__global__ __launch_bounds__(256) void step_k(
    const float* __restrict__ v_in,
    const float* __restrict__ mu, const float* __restrict__ sigma,
    const float* __restrict__ W, const float* __restrict__ erev,
    const float* __restrict__ sens_num, const float* __restrict__ sens_den,
    const float* __restrict__ vleak, const float* __restrict__ gleak,
    const float* __restrict__ cm,
    float* __restrict__ v_out,
    float* __restrict__ out0, float* __restrict__ out1, int write_out)
{
    int j0, b0;
    block_map(blockIdx.x, j0, b0);
    const int tid = threadIdx.x;
    const int jl = tid & (JB - 1), sl = tid / JB;
    const int j = j0 + jl;

    __shared__ float vs[BB][H_];                 // 12 KB: v_pre for 4 batches, all i
    __shared__ float red[2][NSL][BB][JB];        // 8 KB

    for (int idx = tid; idx < BB * H_; idx += 256) {
        int b = idx / H_, i = idx % H_;
        vs[b][i] = v_in[(b0 + b) * H_ + i];
    }
    __syncthreads();

    const float L2E = 1.44269504088896f;
    float num[BB] = {0.f, 0.f, 0.f, 0.f}, den[BB] = {0.f, 0.f, 0.f, 0.f};
    const int ibase = sl * ISL;

    int idx0 = ibase * H_ + j;
    float sg = sigma[idx0], m = mu[idx0], w = W[idx0], e = erev[idx0];
    for (int ii = 0; ii < ISL; ++ii) {
        float sgc = sg, mc = m, wc = w, ec = e;
        if (ii + 1 < ISL) {
            int idx = (ibase + ii + 1) * H_ + j;
            sg = sigma[idx]; m = mu[idx]; w = W[idx]; e = erev[idx];
        }
        float sg2 = sgc * L2E;
        float c   = sg2 * mc;
        float we  = wc * ec;
#pragma unroll
        for (int k = 0; k < BB; ++k) {
            float t  = fmaf(-sg2, vs[k][ibase + ii], c);
            float ex = __builtin_amdgcn_exp2f(t);
            float s  = __builtin_amdgcn_rcpf(1.0f + ex);
            den[k] = fmaf(wc, s, den[k]);
            num[k] = fmaf(we, s, num[k]);
        }
    }
#pragma unroll
    for (int k = 0; k < BB; ++k) {
        red[0][sl][k][jl] = num[k];
        red[1][sl][k][jl] = den[k];
    }
    __syncthreads();

    if (tid < BB * JB) {   // 128 threads: one output each
        int k = tid / JB, l = tid & (JB - 1);
        int jj = j0 + l;
        float n = 0.f, d = 0.f;
#pragma unroll
        for (int s = 0; s < NSL; ++s) { n += red[0][s][k][l]; d += red[1][s][k][l]; }
        int o = (b0 + k) * H_ + jj;
        n += sens_num[o];
        d += sens_den[o];
        float g = gleak[jj];
        float numer = fmaf(cm[jj], vs[k][jj], fmaf(g, vleak[jj], n));
        float denom = cm[jj] + g + d;
        float vn = numer / denom;
        v_out[o] = vn;
        if (write_out) { out0[o] = vn; out1[o] = vn; }
    }
}

// ----------------------------------------------------------------- launch ---
extern "C" void kernel_launch(void* const* d_in, const int* in_sizes, int n_in,
                              void* d_out, int out_size, void* d_ws, size_t ws_size,
                              hipStream_t stream) {
    const float* inputs = (const float*)d_in[0];
    const float* state  = (const float*)d_in[1];
    const float* iw     = (const float*)d_in[2];
    const float* ib     = (const float*)d_in[3];
    const float* smu    = (const float*)d_in[4];
    const float* ssig   = (const float*)d_in[5];
    const float* sW     = (const float*)d_in[6];
    const float* serev  = (const float*)d_in[7];
    const float* mu     = (const float*)d_in[8];
    const float* sigma  = (const float*)d_in[9];
    const float* W      = (const float*)d_in[10];
    const float* erev   = (const float*)d_in[11];
    const float* vleak  = (const float*)d_in[12];
    const float* gleak  = (const float*)d_in[13];
    const float* cm     = (const float*)d_in[14];
    float* out = (float*)d_out;

    float* ws = (float*)d_ws;
    float* sens_num = ws;                    // B*H
    float* sens_den = sens_num + B_ * H_;    // B*H
    float* v0       = sens_den + B_ * H_;    // B*H
    float* v1       = v0 + B_ * H_;          // B*H

    sensory_k<<<NBLK, 256, 0, stream>>>(inputs, iw, ib, smu, ssig, sW, serev,
                                        sens_num, sens_den);

    const float* vin = state;
    for (int t = 0; t < UNFOLDS_; ++t) {
        float* vout = (t & 1) ? v1 : v0;
        int last = (t == UNFOLDS_ - 1);
        step_k<<<NBLK, 256, 0, stream>>>(vin, mu, sigma, W, erev,
                                         sens_num, sens_den, vleak, gleak, cm,
                                         vout, out, out + B_ * H_, last);
        vin = vout;
    }
}

// Round 6
// 213.148 us; speedup vs baseline: 1.7109x; 1.1135x over previous
//
#include <hip/hip_runtime.h>

// LiquidNet (LTC) on MI355X — batch-in-lanes restructure.
// prep_k: transpose+fuse weights into packed[j][i] float4 {c, -sg2, w, w*erev},
//         pack sensory likewise, and build xT[f][b] = inputs*iw+ib.
// part_k: lanes = 64 batches; each wave owns 2 j-columns and one i-slice;
//         weights via wave-uniform float4 loads (read ONCE per step),
//         v via conflict-free LDS; dense partials [sl][nd][H][B].
// fin_k:  reduce 8 step + 8 sensory partial slices, leak + divide, write vT.
// 13 launches: prep, part0(+sensory blocks), fin0, then 5x (part, fin).

constexpr int B_ = 64;
constexpr int F_ = 256;
constexpr int H_ = 768;
constexpr int UNFOLDS_ = 6;

constexpr int NS  = 8;           // reduction slices
constexpr int ISL = H_ / NS;     // 96 i per step slice
constexpr int FSL = F_ / NS;     // 32 f per sensory slice
constexpr int JG  = 96;          // j-groups (8 j per block)
constexpr int STEP_BLOCKS = JG * NS;   // 768
constexpr int SENS_BLOCKS = JG * NS;   // 768
constexpr int FIN_BLOCKS  = (B_ * H_) / 256;  // 192
constexpr int TILE_STEP = (H_ / 32) * (H_ / 32);  // 576
constexpr int TILE_SENS = (F_ / 32) * (H_ / 32);  // 192

// ------------------------------------------------------------------- prep ---
__global__ __launch_bounds__(256) void prep_k(
    const float* __restrict__ sigma, const float* __restrict__ mu,
    const float* __restrict__ W, const float* __restrict__ erev,
    const float* __restrict__ ssig, const float* __restrict__ smu,
    const float* __restrict__ sW, const float* __restrict__ serev,
    const float* __restrict__ inputs, const float* __restrict__ iw,
    const float* __restrict__ ib,
    float4* __restrict__ pk_step,   // [H][H] j-major
    float4* __restrict__ pk_sens,   // [H][F] j-major
    float* __restrict__ xT)         // [F][B]
{
    const int tid = threadIdx.x;
    const float L2E = 1.44269504088896f;
    int blk = blockIdx.x;

    if (blk < TILE_STEP + TILE_SENS) {
        const bool sens = blk >= TILE_STEP;
        if (sens) blk -= TILE_STEP;
        const int ti = blk / 24, tj = blk % 24;     // 24 j-tiles per row
        const int i0 = ti * 32, j0 = tj * 32;
        const float* A0 = sens ? ssig : sigma;
        const float* A1 = sens ? smu : mu;
        const float* A2 = sens ? sW : W;
        const float* A3 = sens ? serev : erev;
        float4* out = sens ? pk_sens : pk_step;
        const int ILEN = sens ? F_ : H_;            // length of i-dim in output row

        __shared__ float tsg[32][33], tmu[32][33], tw[32][33], te[32][33];
        const int col = tid & 31;
#pragma unroll
        for (int k = 0; k < 4; ++k) {
            int row = (tid >> 5) + k * 8;
            int idx = (i0 + row) * H_ + j0 + col;
            tsg[row][col] = A0[idx];
            tmu[row][col] = A1[idx];
            tw [row][col] = A2[idx];
            te [row][col] = A3[idx];
        }
        __syncthreads();
#pragma unroll
        for (int k = 0; k < 4; ++k) {
            int jj = (tid >> 5) + k * 8;
            int ii = tid & 31;
            float sg2 = tsg[ii][jj] * L2E;
            float m   = tmu[ii][jj];
            float w   = tw[ii][jj];
            float e   = te[ii][jj];
            float4 v;
            v.x = sg2 * m;      // c
            v.y = -sg2;         // -sg2
            v.z = w;
            v.w = w * e;
            out[(j0 + jj) * ILEN + (i0 + ii)] = v;
        }
    } else {
        // xT[f][b] = inputs[b][f]*iw[f] + ib[f]
        for (int e = tid; e < B_ * F_; e += 256) {
            int f = e & (F_ - 1), b = e >> 8;
            xT[f * B_ + b] = fmaf(inputs[b * F_ + f], iw[f], ib[f]);
        }
    }
}

// --------------------------------------------------------------- partials ---
// step blocks:   blockIdx < STEP_BLOCKS   -> reduce over i-slice of H
// sensory blocks (only on first step):    -> reduce over f-slice of F
__global__ __launch_bounds__(256) void part_k(
    const float* __restrict__ v_src,   // state [B][H] if first, else vT [H][B]
    int first,
    const float4* __restrict__ pk_step,
    const float4* __restrict__ pk_sens,
    const float* __restrict__ xT,
    float* __restrict__ step_part,     // [NS][2][H][B]
    float* __restrict__ sens_part)     // [NS][2][H][B]
{
    const int tid  = threadIdx.x;
    const int lane = tid & 63;
    const int wv   = __builtin_amdgcn_readfirstlane(tid >> 6);
    __shared__ float vs[ISL * B_];     // 24.6 KB (sensory uses first 8.2 KB)

    int sb = blockIdx.x;
    if (sb < STEP_BLOCKS) {
        const int jg = sb % JG, sl = sb / JG;
        const int i0 = sl * ISL;
        // stage v (transposed) into LDS
        if (first) {
            for (int e = tid; e < ISL * B_; e += 256) {
                int ii = e >> 6, b = e & 63;
                vs[ii * B_ + b] = v_src[b * H_ + i0 + ii];
            }
        } else {
            for (int e = tid; e < ISL * B_; e += 256) {
                int ii = e >> 6, b = e & 63;
                vs[ii * B_ + b] = v_src[(i0 + ii) * B_ + b];
            }
        }
        __syncthreads();

        const int j = jg * 8 + wv * 2;
        const float4* p0 = pk_step + j * H_ + i0;
        const float4* p1 = p0 + H_;
        float n0 = 0.f, d0 = 0.f, n1 = 0.f, d1 = 0.f;
#pragma unroll 4
        for (int ii = 0; ii < ISL; ++ii) {
            float v  = vs[ii * B_ + lane];
            float4 a = p0[ii];
            float4 b4 = p1[ii];
            float t0 = fmaf(a.y, v, a.x);
            float t1 = fmaf(b4.y, v, b4.x);
            float s0 = __builtin_amdgcn_rcpf(1.0f + __builtin_amdgcn_exp2f(t0));
            float s1 = __builtin_amdgcn_rcpf(1.0f + __builtin_amdgcn_exp2f(t1));
            d0 = fmaf(a.z,  s0, d0);
            n0 = fmaf(a.w,  s0, n0);
            d1 = fmaf(b4.z, s1, d1);
            n1 = fmaf(b4.w, s1, n1);
        }
        float* pn = step_part + ((sl * 2 + 0) * H_) * B_;
        float* pd = step_part + ((sl * 2 + 1) * H_) * B_;
        pn[j * B_ + lane]       = n0;
        pd[j * B_ + lane]       = d0;
        pn[(j + 1) * B_ + lane] = n1;
        pd[(j + 1) * B_ + lane] = d1;
    } else {
        const int s = sb - STEP_BLOCKS;
        const int jg = s % JG, sl = s / JG;
        const int f0 = sl * FSL;
        for (int e = tid; e < FSL * B_; e += 256) {
            int ff = e >> 6, b = e & 63;
            vs[ff * B_ + b] = xT[(f0 + ff) * B_ + b];
        }
        __syncthreads();

        const int j = jg * 8 + wv * 2;
        const float4* p0 = pk_sens + j * F_ + f0;
        const float4* p1 = p0 + F_;
        float n0 = 0.f, d0 = 0.f, n1 = 0.f, d1 = 0.f;
#pragma unroll 4
        for (int ff = 0; ff < FSL; ++ff) {
            float v  = vs[ff * B_ + lane];
            float4 a = p0[ff];
            float4 b4 = p1[ff];
            float t0 = fmaf(a.y, v, a.x);
            float t1 = fmaf(b4.y, v, b4.x);
            float s0 = __builtin_amdgcn_rcpf(1.0f + __builtin_amdgcn_exp2f(t0));
            float s1 = __builtin_amdgcn_rcpf(1.0f + __builtin_amdgcn_exp2f(t1));
            d0 = fmaf(a.z,  s0, d0);
            n0 = fmaf(a.w,  s0, n0);
            d1 = fmaf(b4.z, s1, d1);
            n1 = fmaf(b4.w, s1, n1);
        }
        float* pn = sens_part + ((sl * 2 + 0) * H_) * B_;
        float* pd = sens_part + ((sl * 2 + 1) * H_) * B_;
        pn[j * B_ + lane]       = n0;
        pd[j * B_ + lane]       = d0;
        pn[(j + 1) * B_ + lane] = n1;
        pd[(j + 1) * B_ + lane] = d1;
    }
}

// --------------------------------------------------------------- finalize ---
__global__ __launch_bounds__(256) void fin_k(
    const float* __restrict__ v_prev,  // state [B][H] if first, else vT [H][B]
    int first,
    const float* __restrict__ step_part,
    const float* __restrict__ sens_part,
    const float* __restrict__ vleak, const float* __restrict__ gleak,
    const float* __restrict__ cm,
    float* __restrict__ vT_out,        // [H][B]
    float* __restrict__ out0, float* __restrict__ out1, int last)
{
    const int e = blockIdx.x * 256 + threadIdx.x;   // over H*B
    const int b = e & 63, h = e >> 6;

    float n = 0.f, d = 0.f;
#pragma unroll
    for (int sl = 0; sl < NS; ++sl) {
        n += step_part[((sl * 2 + 0) * H_ + h) * B_ + b];
        d += step_part[((sl * 2 + 1) * H_ + h) * B_ + b];
        n += sens_part[((sl * 2 + 0) * H_ + h) * B_ + b];
        d += sens_part[((sl * 2 + 1) * H_ + h) * B_ + b];
    }
    float vp = first ? v_prev[b * H_ + h] : v_prev[h * B_ + b];
    float g  = gleak[h];
    float numer = fmaf(cm[h], vp, fmaf(g, vleak[h], n));
    float denom = cm[h] + g + d;
    float vn = numer / denom;
    vT_out[h * B_ + b] = vn;
    if (last) { out0[b * H_ + h] = vn; out1[b * H_ + h] = vn; }
}

// ----------------------------------------------------------------- launch ---
extern "C" void kernel_launch(void* const* d_in, const int* in_sizes, int n_in,
                              void* d_out, int out_size, void* d_ws, size_t ws_size,
                              hipStream_t stream) {
    const float* inputs = (const float*)d_in[0];
    const float* state  = (const float*)d_in[1];
    const float* iw     = (const float*)d_in[2];
    const float* ib     = (const float*)d_in[3];
    const float* smu    = (const float*)d_in[4];
    const float* ssig   = (const float*)d_in[5];
    const float* sW     = (const float*)d_in[6];
    const float* serev  = (const float*)d_in[7];
    const float* mu     = (const float*)d_in[8];
    const float* sigma  = (const float*)d_in[9];
    const float* W      = (const float*)d_in[10];
    const float* erev   = (const float*)d_in[11];
    const float* vleak  = (const float*)d_in[12];
    const float* gleak  = (const float*)d_in[13];
    const float* cm     = (const float*)d_in[14];
    float* out = (float*)d_out;

    float* ws = (float*)d_ws;
    float4* pk_step = (float4*)ws;                         // H*H float4
    float4* pk_sens = pk_step + H_ * H_;                   // H*F float4
    float*  xT      = (float*)(pk_sens + H_ * F_);         // F*B
    float*  step_part = xT + F_ * B_;                      // NS*2*H*B
    float*  sens_part = step_part + NS * 2 * H_ * B_;      // NS*2*H*B
    float*  vT0       = sens_part + NS * 2 * H_ * B_;      // H*B
    float*  vT1       = vT0 + H_ * B_;                     // H*B

    prep_k<<<TILE_STEP + TILE_SENS + 1, 256, 0, stream>>>(
        sigma, mu, W, erev, ssig, smu, sW, serev, inputs, iw, ib,
        pk_step, pk_sens, xT);

    for (int t = 0; t < UNFOLDS_; ++t) {
        const int first = (t == 0);
        const int last  = (t == UNFOLDS_ - 1);
        const float* vsrc = first ? state : ((t & 1) ? vT0 : vT1);
        float* vdst = (t & 1) ? vT1 : vT0;
        int nblk = first ? (STEP_BLOCKS + SENS_BLOCKS) : STEP_BLOCKS;
        part_k<<<nblk, 256, 0, stream>>>(vsrc, first, pk_step, pk_sens, xT,
                                         step_part, sens_part);
        fin_k<<<FIN_BLOCKS, 256, 0, stream>>>(vsrc, first, step_part, sens_part,
                                              vleak, gleak, cm, vdst,
                                              out, out + B_ * H_, last);
    }
}